// Round 1
// baseline (504.768 us; speedup 1.0000x reference)
//
#include <hip/hip_runtime.h>
#include <math.h>

// SubsetOperator: relaxed top-K (K=16) Gumbel-softmax, rows of N=4096.
// Exp-domain reformulation: e_i *= max(1 - p_i, EPS) replaces the reference's
// s += log(max(1-p,EPS)); softmax(s) — algebraically identical, zero
// per-iteration transcendentals.

#define ROW_N 4096
#define THREADS 256
#define VPT 16   // elements per thread
#define V4 4     // float4s per thread

__device__ __forceinline__ float wave_reduce_sum(float v) {
#pragma unroll
    for (int off = 32; off > 0; off >>= 1)
        v += __shfl_xor(v, off, 64);
    return v;
}

__device__ __forceinline__ float wave_reduce_max(float v) {
#pragma unroll
    for (int off = 32; off > 0; off >>= 1)
        v = fmaxf(v, __shfl_xor(v, off, 64));
    return v;
}

__global__ __launch_bounds__(THREADS) void subset_topk_kernel(
    const float* __restrict__ scores,
    const float* __restrict__ gnoise,
    float* __restrict__ out)
{
    constexpr float EPS = 1.17549435e-38f;  // np.finfo(float32).tiny

    __shared__ float red[2][4];

    const size_t base = (size_t)blockIdx.x * ROW_N;
    const float4* s4 = (const float4*)(scores + base);
    const float4* g4 = (const float4*)(gnoise + base);
    float4* o4 = (float4*)(out + base);

    const int t = threadIdx.x;
    const int wave = t >> 6;
    const int lane = t & 63;

    // ---- load s0 = scores + g (coalesced float4) ----
    float s0[VPT];
#pragma unroll
    for (int j = 0; j < V4; ++j) {
        float4 a = s4[t + j * THREADS];
        float4 b = g4[t + j * THREADS];
        s0[j * 4 + 0] = a.x + b.x;
        s0[j * 4 + 1] = a.y + b.y;
        s0[j * 4 + 2] = a.z + b.z;
        s0[j * 4 + 3] = a.w + b.w;
    }

    // ---- block max of s0 ----
    float lm = s0[0];
#pragma unroll
    for (int i = 1; i < VPT; ++i) lm = fmaxf(lm, s0[i]);
    lm = wave_reduce_max(lm);
    if (lane == 0) red[0][wave] = lm;
    __syncthreads();
    const float m = fmaxf(fmaxf(red[0][0], red[0][1]),
                          fmaxf(red[0][2], red[0][3]));

    // ---- e = exp(s0 - m), khot = 0 ----
    float e[VPT];
    float kh[VPT];
#pragma unroll
    for (int i = 0; i < VPT; ++i) {
        e[i] = __expf(s0[i] - m);
        kh[i] = 0.0f;
    }

    // ---- 16 rounds: sum -> p -> accumulate -> mask ----
    int buf = 1;
#pragma unroll
    for (int k = 0; k < 16; ++k) {
        float ls = 0.0f;
#pragma unroll
        for (int i = 0; i < VPT; ++i) ls += e[i];
        ls = wave_reduce_sum(ls);
        if (lane == 0) red[buf][wave] = ls;
        __syncthreads();
        const float S = (red[buf][0] + red[buf][1]) +
                        (red[buf][2] + red[buf][3]);
        buf ^= 1;
        const float invS = 1.0f / S;
        if (k < 15) {
#pragma unroll
            for (int i = 0; i < VPT; ++i) {
                const float p = e[i] * invS;
                kh[i] += p;
                e[i] *= fmaxf(1.0f - p, EPS);
            }
        } else {
#pragma unroll
            for (int i = 0; i < VPT; ++i) {
                kh[i] += e[i] * invS;
            }
        }
    }

    // ---- store khot (coalesced float4) ----
#pragma unroll
    for (int j = 0; j < V4; ++j) {
        float4 o;
        o.x = kh[j * 4 + 0];
        o.y = kh[j * 4 + 1];
        o.z = kh[j * 4 + 2];
        o.w = kh[j * 4 + 3];
        o4[t + j * THREADS] = o;
    }
}

extern "C" void kernel_launch(void* const* d_in, const int* in_sizes, int n_in,
                              void* d_out, int out_size, void* d_ws, size_t ws_size,
                              hipStream_t stream) {
    const float* scores = (const float*)d_in[0];
    const float* gnoise = (const float*)d_in[1];
    float* out = (float*)d_out;

    const int rows = in_sizes[0] / ROW_N;  // 4 * 2048 = 8192
    subset_topk_kernel<<<rows, THREADS, 0, stream>>>(scores, gnoise, out);
}

// Round 2
// 327.817 us; speedup vs baseline: 1.5398x; 1.5398x over previous
//
#include <hip/hip_runtime.h>
#include <math.h>

// SubsetOperator: relaxed top-K (K=16) Gumbel-softmax, rows of N=4096.
// Exp-domain recurrence (R1, verified): e_i *= max(1-p_i, EPS) replaces
// s += log(max(1-p,EPS)); softmax(s).
//
// R2: one WAVE per row (no __syncthreads, no LDS). 256-thread block = 4
// independent rows. Each lane holds 64 elements (16 x float4) of e and kh
// in registers. All reductions are 6 x __shfl_xor within the wave.

#define ROW_N 4096
#define C4 16   // float4 chunks per lane (64 elements / lane)

__device__ __forceinline__ float wave_reduce_sum(float v) {
#pragma unroll
    for (int off = 32; off > 0; off >>= 1)
        v += __shfl_xor(v, off, 64);
    return v;
}

__device__ __forceinline__ float wave_reduce_max(float v) {
#pragma unroll
    for (int off = 32; off > 0; off >>= 1)
        v = fmaxf(v, __shfl_xor(v, off, 64));
    return v;
}

__global__ __launch_bounds__(256, 3) void subset_topk_kernel(
    const float* __restrict__ scores,
    const float* __restrict__ gnoise,
    float* __restrict__ out)
{
    constexpr float EPS = 1.17549435e-38f;  // np.finfo(float32).tiny

    const int wave = threadIdx.x >> 6;
    const int lane = threadIdx.x & 63;
    const int row  = blockIdx.x * 4 + wave;

    const size_t base = (size_t)row * ROW_N;
    const float4* s4 = (const float4*)(scores + base);
    const float4* g4 = (const float4*)(gnoise + base);
    float4*       o4 = (float4*)(out + base);

    // ---- load s0 = scores + g into e[] (coalesced float4) ----
    float4 e[C4];
#pragma unroll
    for (int j = 0; j < C4; ++j) {
        float4 a = s4[j * 64 + lane];
        float4 b = g4[j * 64 + lane];
        e[j].x = a.x + b.x;
        e[j].y = a.y + b.y;
        e[j].z = a.z + b.z;
        e[j].w = a.w + b.w;
    }

    // ---- wave max of s0 (binary tree over chunks, then horizontal, then shfl) ----
    float4 m4[C4];
#pragma unroll
    for (int j = 0; j < 8; ++j) {
        m4[j].x = fmaxf(e[j].x, e[j + 8].x);
        m4[j].y = fmaxf(e[j].y, e[j + 8].y);
        m4[j].z = fmaxf(e[j].z, e[j + 8].z);
        m4[j].w = fmaxf(e[j].w, e[j + 8].w);
    }
#pragma unroll
    for (int j = 0; j < 4; ++j) {
        m4[j].x = fmaxf(m4[j].x, m4[j + 4].x);
        m4[j].y = fmaxf(m4[j].y, m4[j + 4].y);
        m4[j].z = fmaxf(m4[j].z, m4[j + 4].z);
        m4[j].w = fmaxf(m4[j].w, m4[j + 4].w);
    }
    float4 mm;
    mm.x = fmaxf(fmaxf(m4[0].x, m4[2].x), fmaxf(m4[1].x, m4[3].x));
    mm.y = fmaxf(fmaxf(m4[0].y, m4[2].y), fmaxf(m4[1].y, m4[3].y));
    mm.z = fmaxf(fmaxf(m4[0].z, m4[2].z), fmaxf(m4[1].z, m4[3].z));
    mm.w = fmaxf(fmaxf(m4[0].w, m4[2].w), fmaxf(m4[1].w, m4[3].w));
    float m = fmaxf(fmaxf(mm.x, mm.y), fmaxf(mm.z, mm.w));
    m = wave_reduce_max(m);

    // ---- e = exp(s0 - m), kh = 0 ----
    float4 kh[C4];
#pragma unroll
    for (int j = 0; j < C4; ++j) {
        e[j].x = __expf(e[j].x - m);
        e[j].y = __expf(e[j].y - m);
        e[j].z = __expf(e[j].z - m);
        e[j].w = __expf(e[j].w - m);
        kh[j].x = 0.0f; kh[j].y = 0.0f; kh[j].z = 0.0f; kh[j].w = 0.0f;
    }

    // ---- 16 rounds: tree-sum -> p -> accumulate -> mask ----
    for (int k = 0; k < 16; ++k) {
        // binary-tree partial sum (short dep chain)
        float4 t[8];
#pragma unroll
        for (int j = 0; j < 8; ++j) {
            t[j].x = e[j].x + e[j + 8].x;
            t[j].y = e[j].y + e[j + 8].y;
            t[j].z = e[j].z + e[j + 8].z;
            t[j].w = e[j].w + e[j + 8].w;
        }
#pragma unroll
        for (int j = 0; j < 4; ++j) {
            t[j].x += t[j + 4].x;
            t[j].y += t[j + 4].y;
            t[j].z += t[j + 4].z;
            t[j].w += t[j + 4].w;
        }
        float4 u;
        u.x = (t[0].x + t[2].x) + (t[1].x + t[3].x);
        u.y = (t[0].y + t[2].y) + (t[1].y + t[3].y);
        u.z = (t[0].z + t[2].z) + (t[1].z + t[3].z);
        u.w = (t[0].w + t[2].w) + (t[1].w + t[3].w);
        float ls = (u.x + u.y) + (u.z + u.w);
        ls = wave_reduce_sum(ls);

        const float invS = __builtin_amdgcn_rcpf(ls);
#pragma unroll
        for (int j = 0; j < C4; ++j) {
            float px = e[j].x * invS;
            float py = e[j].y * invS;
            float pz = e[j].z * invS;
            float pw = e[j].w * invS;
            kh[j].x += px; kh[j].y += py; kh[j].z += pz; kh[j].w += pw;
            e[j].x *= fmaxf(1.0f - px, EPS);
            e[j].y *= fmaxf(1.0f - py, EPS);
            e[j].z *= fmaxf(1.0f - pz, EPS);
            e[j].w *= fmaxf(1.0f - pw, EPS);
        }
    }

    // ---- store khot (coalesced float4) ----
#pragma unroll
    for (int j = 0; j < C4; ++j) {
        o4[j * 64 + lane] = kh[j];
    }
}

extern "C" void kernel_launch(void* const* d_in, const int* in_sizes, int n_in,
                              void* d_out, int out_size, void* d_ws, size_t ws_size,
                              hipStream_t stream) {
    const float* scores = (const float*)d_in[0];
    const float* gnoise = (const float*)d_in[1];
    float* out = (float*)d_out;

    const int rows = in_sizes[0] / ROW_N;   // 8192
    const int blocks = rows / 4;            // 4 rows (waves) per 256-thread block
    subset_topk_kernel<<<blocks, 256, 0, stream>>>(scores, gnoise, out);
}